// Round 3
// baseline (1760.433 us; speedup 1.0000x reference)
//
#include <hip/hip_runtime.h>
#include <math.h>

#define NCB 4
#define NE 1024
#define DIM 64
#define BQ 8
#define HH 128
#define WW 128
#define HW (HH*WW)             // 16384
#define NPIX (BQ*HH*WW)        // 131072
#define NWAVES (NPIX/64)       // 2048 total waves
#define MSE_DENOM 8388608.0f   // NPIX*DIM
#define EPSF 1e-5f

// ---------------- kernel 0: per-code squared norms ----------------
__global__ __launch_bounds__(64) void rvq_norms(const float* __restrict__ cb,
                                                float* __restrict__ norms) {
    int code = blockIdx.x * 64 + threadIdx.x;  // 0..4095
    const float4* row = reinterpret_cast<const float4*>(cb + (size_t)code * DIM);
    float s0 = 0.f, s1 = 0.f, s2 = 0.f, s3 = 0.f;
#pragma unroll
    for (int k = 0; k < 16; ++k) {
        float4 v = row[k];
        s0 = fmaf(v.x, v.x, s0); s1 = fmaf(v.y, v.y, s1);
        s2 = fmaf(v.z, v.z, s2); s3 = fmaf(v.w, v.w, s3);
    }
    norms[code] = (s0 + s1) + (s2 + s3);
}

// ---------------- kernel 1: main RVQ (LDS-free, scalar-pipe codebook) ----
// 512 blocks x 256 threads; thread = pixel; each WAVE independently scans
// all codes for its 64 lanes' pixels. Code index j is wave-uniform =>
// e-row reads become s_load (SMEM pipe, SGPR operands to v_fma), removing
// the 134M ds_read_b128 broadcasts that bottlenecked the LDS pipe (~8cyc
// per 16B broadcast = 1.75ms). No LDS, no barriers, per-lane serial argmin
// (ascending j, strict <) = exact jnp.argmin first-min semantics.
__global__ __launch_bounds__(256, 4) void rvq_main(
    const float* __restrict__ z, const float* __restrict__ cb,
    const float* __restrict__ norms,
    float* __restrict__ out_zq, float* __restrict__ out_idx,
    unsigned* __restrict__ hist, float* __restrict__ msePartial)
{
    const int tid = threadIdx.x;
    const int flat = blockIdx.x * 256 + tid;       // pixel id
    const int lane = tid & 63;
    const int gw = flat >> 6;                      // global wave id 0..2047

    const int b = flat >> 14;
    const int y = (flat >> 7) & 127;
    const int x = flat & 127;
    const size_t zbase = (size_t)b * DIM * HW + (size_t)y * WW + x;

    float r[DIM];
#pragma unroll
    for (int c = 0; c < DIM; ++c) r[c] = z[zbase + (size_t)c * HW];

    for (int i = 0; i < NCB; ++i) {
        const float* cbi = cb + (size_t)i * NE * DIM;
        const float* nrm = norms + i * NE;
        float bd = 3.4e38f; int bidx = 0;

        for (int j = 0; j < NE; ++j) {
            const float* e = cbi + j * DIM;        // uniform addr -> s_load
            float d0 = 0.f, d1 = 0.f, d2 = 0.f, d3 = 0.f;
#pragma unroll
            for (int k = 0; k < 16; ++k) {
                d0 = fmaf(r[4 * k + 0], e[4 * k + 0], d0);
                d1 = fmaf(r[4 * k + 1], e[4 * k + 1], d1);
                d2 = fmaf(r[4 * k + 2], e[4 * k + 2], d2);
                d3 = fmaf(r[4 * k + 3], e[4 * k + 3], d3);
            }
            float dist = fmaf(-2.0f, (d0 + d1) + (d2 + d3), nrm[j]);
            if (dist < bd) { bd = dist; bidx = j; }   // first-min, per lane
        }

        // residual update: divergent gather of the chosen row (L2-resident)
        const float4* e4 = reinterpret_cast<const float4*>(cbi + (size_t)bidx * DIM);
#pragma unroll
        for (int k = 0; k < 16; ++k) {
            float4 ev = e4[k];
            r[4 * k + 0] -= ev.x; r[4 * k + 1] -= ev.y;
            r[4 * k + 2] -= ev.z; r[4 * k + 3] -= ev.w;
        }

        // index output: (b, h, w, ph*4+pw, cb)
        {
            int hh = y >> 2, ww = x >> 2, pp = ((y & 3) << 2) + (x & 3);
            size_t off = (size_t)b * 65536 + (size_t)hh * 2048 + (size_t)ww * 64
                       + (size_t)pp * 4 + i;
            out_idx[off] = (float)bidx;
        }
        atomicAdd(&hist[i * NE + bidx], 1u);

        // MSE contribution: (z_q - r_old)^2 = r_new^2, wave-reduced
        float s = 0.f;
#pragma unroll
        for (int c = 0; c < DIM; ++c) s = fmaf(r[c], r[c], s);
#pragma unroll
        for (int d_ = 32; d_ > 0; d_ >>= 1) s += __shfl_down(s, d_, 64);
        if (lane == 0) msePartial[i * NWAVES + gw] = s;
    }

    // z_q = z - r_final (telescoped straight-through sum); coalesced
#pragma unroll
    for (int c = 0; c < DIM; ++c) {
        size_t o = zbase + (size_t)c * HW;
        out_zq[o] = z[o] - r[c];
    }
}

// ---------------- kernel 2: deterministic loss finalize ----------------
__global__ __launch_bounds__(1024) void rvq_finalize(
    const unsigned* __restrict__ hist, const float* __restrict__ msePartial,
    float* __restrict__ out_loss)
{
    __shared__ float red[1024];
    int t = threadIdx.x;
    float loss = 0.f;
    for (int i = 0; i < NCB; ++i) {
        // usage entropy: probs = (cnt+eps)/(131072+eps*1024); H=-sum p*log(p+eps)
        float cnt = (float)hist[i * NE + t];
        float prob = (cnt + EPSF) / (131072.0f + EPSF * 1024.0f);
        red[t] = -prob * logf(prob + EPSF);
        __syncthreads();
        for (int s = 512; s > 0; s >>= 1) { if (t < s) red[t] += red[t + s]; __syncthreads(); }
        float entropy = red[0];
        __syncthreads();
        // mse sum
        red[t] = msePartial[i * NWAVES + t] + msePartial[i * NWAVES + 1024 + t];
        __syncthreads();
        for (int s = 512; s > 0; s >>= 1) { if (t < s) red[t] += red[t + s]; __syncthreads(); }
        float mse_sum = red[0];
        __syncthreads();
        loss += 0.25f * (mse_sum / MSE_DENOM) + 0.01f * (logf(1024.0f) - entropy);
    }
    if (t == 0) out_loss[0] = loss;
}

extern "C" void kernel_launch(void* const* d_in, const int* in_sizes, int n_in,
                              void* d_out, int out_size, void* d_ws, size_t ws_size,
                              hipStream_t stream) {
    const float* z  = (const float*)d_in[0];
    const float* cb = (const float*)d_in[1];

    float* out      = (float*)d_out;
    float* out_zq   = out;                    // 8388608
    float* out_loss = out + 8388608;          // 1
    float* out_idx  = out + 8388609;          // 524288 (indices as float)

    unsigned* hist       = (unsigned*)d_ws;                       // 4*1024 u32 = 16 KB
    float*    norms      = (float*)((char*)d_ws + 16384);         // 4*1024 f32 = 16 KB
    float*    msePartial = (float*)((char*)d_ws + 32768);         // 4*2048 f32 = 32 KB

    hipMemsetAsync(d_ws, 0, 16384, stream);   // zero histogram every call (deterministic)
    rvq_norms<<<64, 64, 0, stream>>>(cb, norms);
    rvq_main<<<512, 256, 0, stream>>>(z, cb, norms, out_zq, out_idx, hist, msePartial);
    rvq_finalize<<<1, 1024, 0, stream>>>(hist, msePartial, out_loss);
}

// Round 4
// 458.832 us; speedup vs baseline: 3.8368x; 3.8368x over previous
//
#include <hip/hip_runtime.h>
#include <math.h>

typedef __attribute__((ext_vector_type(8))) short short8;
typedef __attribute__((ext_vector_type(4))) float f32x4;

#define NCB 4
#define NE 1024
#define DIM 64
#define HW 16384
#define NPIX 131072
#define NWAVES 4096            // 1024 blocks * 4 waves
#define MSE_DENOM 8388608.0f   // NPIX*DIM
#define EPSF 1e-5f

__device__ __forceinline__ unsigned short f2bf(float x) {  // RNE fp32->bf16
    unsigned u = __float_as_uint(x);
    u += 0x7fffu + ((u >> 16) & 1u);
    return (unsigned short)(u >> 16);
}
__device__ __forceinline__ float bf2f(unsigned short h) {  // exact bf16->fp32
    return __uint_as_float(((unsigned)h) << 16);
}

// ---------------- kernel 0: per-code squared norms (fp32, exact) ----------
__global__ __launch_bounds__(64) void rvq_norms(const float* __restrict__ cb,
                                                float* __restrict__ norms) {
    int code = blockIdx.x * 64 + threadIdx.x;  // 0..4095
    const float4* row = reinterpret_cast<const float4*>(cb + (size_t)code * DIM);
    float s0 = 0.f, s1 = 0.f, s2 = 0.f, s3 = 0.f;
#pragma unroll
    for (int k = 0; k < 16; ++k) {
        float4 v = row[k];
        s0 = fmaf(v.x, v.x, s0); s1 = fmaf(v.y, v.y, s1);
        s2 = fmaf(v.z, v.z, s2); s3 = fmaf(v.w, v.w, s3);
    }
    norms[code] = (s0 + s1) + (s2 + s3);
}

// ---------------- kernel 1: MFMA RVQ (bf16x3 fp32-emulated distances) -----
// 1024 blocks x 256 threads (4 waves). Wave owns M=32 pixels (2 MFMA row-
// tiles of 16). r kept in registers laid out as A-frags:
//   lane L holds rows {wid*32 + m*16 + (L&15)}, dims kh*32 + (L>>4)*8 + e.
// Per 64-code chunk: stage fp32 codebook, split bf16x3 in-register, write
// XOR-swizzled LDS (addr = lin ^ ((code&7)<<4) -> <=2-way banks). 6 products
// (a1b1,a1b2,a2b1,a1b3,a2b2,a3b1) x 2 k-halves accumulate into fp32 C
// initialized to -0.5*||e||^2; dist = -2*acc (||r||^2 shift is argmin-
// invariant). Strict-< scan + idx tie-break shfl reduce = jnp.argmin.
__global__ __launch_bounds__(256, 2) void rvq_main(
    const float* __restrict__ z, const float* __restrict__ cb,
    const float* __restrict__ norms,
    float* __restrict__ out_zq, float* __restrict__ out_idx,
    unsigned* __restrict__ hist, float* __restrict__ msePartial)
{
    __shared__ unsigned short sB[3 * 4096];  // 24 KB: [split][64 codes][64 dims] bf16, swizzled
    __shared__ float sN[64];
    __shared__ int   sBest[4][32];

    const int tid  = threadIdx.x;
    const int lane = tid & 63;
    const int wid  = tid >> 6;
    const int col  = lane & 15;   // MFMA col / A-row within tile
    const int g    = lane >> 4;   // k-group (8 dims)
    const int blockPix = blockIdx.x * 128;
    char* sBc = reinterpret_cast<char*>(sB);

    int pf[2]; size_t zb[2];
#pragma unroll
    for (int m = 0; m < 2; ++m) {
        pf[m] = blockPix + wid * 32 + m * 16 + col;
        zb[m] = (size_t)(pf[m] >> 14) * 1048576 + (size_t)(pf[m] & 16383);
    }

    float r[2][2][8];   // [m][kh][e], dim = kh*32 + g*8 + e
#pragma unroll
    for (int m = 0; m < 2; ++m)
#pragma unroll
        for (int kh = 0; kh < 2; ++kh)
#pragma unroll
            for (int e = 0; e < 8; ++e)
                r[m][kh][e] = z[zb[m] + (size_t)(kh * 32 + g * 8 + e) * HW];

    for (int i = 0; i < NCB; ++i) {
        const float* cbi = cb + (size_t)i * NE * DIM;

        // bf16x3 split of r -> A-frags
        short8 A[3][2][2];
#pragma unroll
        for (int m = 0; m < 2; ++m)
#pragma unroll
            for (int kh = 0; kh < 2; ++kh)
#pragma unroll
                for (int e = 0; e < 8; ++e) {
                    float t = r[m][kh][e];
                    unsigned short u1 = f2bf(t); t -= bf2f(u1);
                    unsigned short u2 = f2bf(t); t -= bf2f(u2);
                    unsigned short u3 = f2bf(t);
                    A[0][m][kh][e] = (short)u1;
                    A[1][m][kh][e] = (short)u2;
                    A[2][m][kh][e] = (short)u3;
                }

        float minv[2][4]; int mini[2][4];
#pragma unroll
        for (int m = 0; m < 2; ++m)
#pragma unroll
            for (int rr = 0; rr < 4; ++rr) { minv[m][rr] = 3.4e38f; mini[m][rr] = 0; }

        for (int c0 = 0; c0 < NE; c0 += 64) {
            __syncthreads();   // previous chunk fully consumed
            {   // stage 64 codes: thread t -> code t>>2, dims (t&3)*16..+15
                int code = tid >> 2, dg = tid & 3;
                const float4* s4 = reinterpret_cast<const float4*>(
                    cbi + (size_t)(c0 + code) * DIM + dg * 16);
                float v[16];
                {
                    float4 q;
                    q = s4[0]; v[0]=q.x; v[1]=q.y; v[2]=q.z; v[3]=q.w;
                    q = s4[1]; v[4]=q.x; v[5]=q.y; v[6]=q.z; v[7]=q.w;
                    q = s4[2]; v[8]=q.x; v[9]=q.y; v[10]=q.z; v[11]=q.w;
                    q = s4[3]; v[12]=q.x; v[13]=q.y; v[14]=q.z; v[15]=q.w;
                }
                int linbase = code * 128 + dg * 32;
                int sw = (code & 7) << 4;
#pragma unroll
                for (int h = 0; h < 2; ++h) {
                    short8 p1, p2, p3;
#pragma unroll
                    for (int e = 0; e < 8; ++e) {
                        float t = v[h * 8 + e];
                        unsigned short u1 = f2bf(t); t -= bf2f(u1);
                        unsigned short u2 = f2bf(t); t -= bf2f(u2);
                        unsigned short u3 = f2bf(t);
                        p1[e] = (short)u1; p2[e] = (short)u2; p3[e] = (short)u3;
                    }
                    int a = (linbase + h * 16) ^ sw;
                    *reinterpret_cast<short8*>(sBc + a)         = p1;
                    *reinterpret_cast<short8*>(sBc + 8192 + a)  = p2;
                    *reinterpret_cast<short8*>(sBc + 16384 + a) = p3;
                }
                if (tid < 64) sN[tid] = norms[i * NE + c0 + tid];
            }
            __syncthreads();

#pragma unroll
            for (int sub = 0; sub < 4; ++sub) {
                int code = sub * 16 + col;
                int sw = (code & 7) << 4;
                short8 B[3][2];
#pragma unroll
                for (int s = 0; s < 3; ++s)
#pragma unroll
                    for (int kh = 0; kh < 2; ++kh) {
                        int a = ((code << 7) + (kh << 6) + (g << 4)) ^ sw;
                        B[s][kh] = *reinterpret_cast<const short8*>(sBc + s * 8192 + a);
                    }
                float nrm = sN[code];
                f32x4 acc[2][2];
#pragma unroll
                for (int m = 0; m < 2; ++m)
#pragma unroll
                    for (int rr = 0; rr < 4; ++rr) {
                        acc[m][0][rr] = -0.5f * nrm;
                        acc[m][1][rr] = 0.f;
                    }
#pragma unroll
                for (int m = 0; m < 2; ++m)
#pragma unroll
                    for (int kh = 0; kh < 2; ++kh) {
                        acc[m][kh] = __builtin_amdgcn_mfma_f32_16x16x32_bf16(A[0][m][kh], B[0][kh], acc[m][kh], 0, 0, 0);
                        acc[m][kh] = __builtin_amdgcn_mfma_f32_16x16x32_bf16(A[0][m][kh], B[1][kh], acc[m][kh], 0, 0, 0);
                        acc[m][kh] = __builtin_amdgcn_mfma_f32_16x16x32_bf16(A[1][m][kh], B[0][kh], acc[m][kh], 0, 0, 0);
                        acc[m][kh] = __builtin_amdgcn_mfma_f32_16x16x32_bf16(A[0][m][kh], B[2][kh], acc[m][kh], 0, 0, 0);
                        acc[m][kh] = __builtin_amdgcn_mfma_f32_16x16x32_bf16(A[1][m][kh], B[1][kh], acc[m][kh], 0, 0, 0);
                        acc[m][kh] = __builtin_amdgcn_mfma_f32_16x16x32_bf16(A[2][m][kh], B[0][kh], acc[m][kh], 0, 0, 0);
                    }
#pragma unroll
                for (int m = 0; m < 2; ++m)
#pragma unroll
                    for (int rr = 0; rr < 4; ++rr) {
                        float dist = -2.0f * (acc[m][0][rr] + acc[m][1][rr]);
                        if (dist < minv[m][rr]) { minv[m][rr] = dist; mini[m][rr] = c0 + code; }
                    }
            }
        }

        // cross-lane argmin within each 16-lane row-group, idx tie-break
#pragma unroll
        for (int m = 0; m < 2; ++m)
#pragma unroll
            for (int rr = 0; rr < 4; ++rr) {
                float v = minv[m][rr]; int ix = mini[m][rr];
#pragma unroll
                for (int off = 1; off < 16; off <<= 1) {
                    float ov = __shfl_xor(v, off, 64);
                    int   oi = __shfl_xor(ix, off, 64);
                    if (ov < v || (ov == v && oi < ix)) { v = ov; ix = oi; }
                }
                minv[m][rr] = v; mini[m][rr] = ix;
            }
        __syncthreads();
        if (col == 0) {   // lane holds D-rows (g*4+rr); one writer per group
#pragma unroll
            for (int m = 0; m < 2; ++m)
#pragma unroll
                for (int rr = 0; rr < 4; ++rr)
                    sBest[wid][m * 16 + g * 4 + rr] = mini[m][rr];
        }
        __syncthreads();
        int best[2];
        best[0] = sBest[wid][col];
        best[1] = sBest[wid][16 + col];

        if (lane < 16) {  // idx output + histogram, one writer per row
#pragma unroll
            for (int m = 0; m < 2; ++m) {
                int pfr = blockPix + wid * 32 + m * 16 + lane;
                int bb = pfr >> 14, yy = (pfr >> 7) & 127, xx = pfr & 127;
                int bi = sBest[wid][m * 16 + lane];
                size_t off = (size_t)bb * 65536 + (size_t)(yy >> 2) * 2048
                           + (size_t)(xx >> 2) * 64
                           + (size_t)(((yy & 3) << 2) + (xx & 3)) * 4 + (size_t)i;
                out_idx[off] = (float)bi;
                atomicAdd(&hist[i * NE + bi], 1u);
            }
        }

        // residual update from ORIGINAL fp32 codebook (keeps r exact)
#pragma unroll
        for (int m = 0; m < 2; ++m) {
            const float* er = cbi + (size_t)best[m] * DIM;
#pragma unroll
            for (int kh = 0; kh < 2; ++kh) {
                const float4* e4 = reinterpret_cast<const float4*>(er + kh * 32 + g * 8);
                float4 q0 = e4[0], q1 = e4[1];
                r[m][kh][0] -= q0.x; r[m][kh][1] -= q0.y;
                r[m][kh][2] -= q0.z; r[m][kh][3] -= q0.w;
                r[m][kh][4] -= q1.x; r[m][kh][5] -= q1.y;
                r[m][kh][6] -= q1.z; r[m][kh][7] -= q1.w;
            }
        }

        // MSE partial: (z_q - r_old)^2 = r_new^2
        float s = 0.f;
#pragma unroll
        for (int m = 0; m < 2; ++m)
#pragma unroll
            for (int kh = 0; kh < 2; ++kh)
#pragma unroll
                for (int e = 0; e < 8; ++e) s = fmaf(r[m][kh][e], r[m][kh][e], s);
#pragma unroll
        for (int d_ = 32; d_ > 0; d_ >>= 1) s += __shfl_down(s, d_, 64);
        if (lane == 0) msePartial[i * NWAVES + blockIdx.x * 4 + wid] = s;
    }

    // epilogue: z_q = z - r_final (telescoped straight-through sum)
#pragma unroll
    for (int m = 0; m < 2; ++m)
#pragma unroll
        for (int kh = 0; kh < 2; ++kh)
#pragma unroll
            for (int e = 0; e < 8; ++e) {
                size_t o = zb[m] + (size_t)(kh * 32 + g * 8 + e) * HW;
                out_zq[o] = z[o] - r[m][kh][e];
            }
}

// ---------------- kernel 2: deterministic loss finalize ----------------
__global__ __launch_bounds__(1024) void rvq_finalize(
    const unsigned* __restrict__ hist, const float* __restrict__ msePartial,
    float* __restrict__ out_loss)
{
    __shared__ float red[1024];
    int t = threadIdx.x;
    float loss = 0.f;
    for (int i = 0; i < NCB; ++i) {
        float cnt = (float)hist[i * NE + t];
        float prob = (cnt + EPSF) / (131072.0f + EPSF * 1024.0f);
        red[t] = -prob * logf(prob + EPSF);
        __syncthreads();
        for (int s = 512; s > 0; s >>= 1) { if (t < s) red[t] += red[t + s]; __syncthreads(); }
        float entropy = red[0];
        __syncthreads();
        red[t] = msePartial[i * NWAVES + t]        + msePartial[i * NWAVES + 1024 + t]
               + msePartial[i * NWAVES + 2048 + t] + msePartial[i * NWAVES + 3072 + t];
        __syncthreads();
        for (int s = 512; s > 0; s >>= 1) { if (t < s) red[t] += red[t + s]; __syncthreads(); }
        float mse_sum = red[0];
        __syncthreads();
        loss += 0.25f * (mse_sum / MSE_DENOM) + 0.01f * (logf(1024.0f) - entropy);
    }
    if (t == 0) out_loss[0] = loss;
}

extern "C" void kernel_launch(void* const* d_in, const int* in_sizes, int n_in,
                              void* d_out, int out_size, void* d_ws, size_t ws_size,
                              hipStream_t stream) {
    const float* z  = (const float*)d_in[0];
    const float* cb = (const float*)d_in[1];

    float* out      = (float*)d_out;
    float* out_zq   = out;                    // 8388608
    float* out_loss = out + 8388608;          // 1
    float* out_idx  = out + 8388609;          // 524288 (indices as float)

    unsigned* hist       = (unsigned*)d_ws;                       // 16 KB
    float*    norms      = (float*)((char*)d_ws + 16384);         // 16 KB
    float*    msePartial = (float*)((char*)d_ws + 32768);         // 64 KB

    hipMemsetAsync(d_ws, 0, 16384, stream);   // zero histogram (deterministic)
    rvq_norms<<<64, 64, 0, stream>>>(cb, norms);
    rvq_main<<<1024, 256, 0, stream>>>(z, cb, norms, out_zq, out_idx, hist, msePartial);
    rvq_finalize<<<1, 1024, 0, stream>>>(hist, msePartial, out_loss);
}